// Round 2
// baseline (218.517 us; speedup 1.0000x reference)
//
#include <hip/hip_runtime.h>
#include <hip/hip_bf16.h>

#define BATCH   64
#define C_IN    512
#define C_OUT   512
#define SPATIAL 784          // 28*28
#define KSMALL  256          // K = C_OUT * 0.5
#define RATE    0.5f

// ---------------------------------------------------------------------------
// Kernel 1: s[b][c] = mean(|x[b,c,:,:]|).  One wave per (b,c) pair.
// 784 floats = 196 float4 per pair, contiguous, 16B-aligned (3136 B stride).
// This phase reads 64*512*784*4 B = 102.8 MB -> memory-bound floor ~17 us.
// ---------------------------------------------------------------------------
__global__ __launch_bounds__(256) void absmean_kernel(const float* __restrict__ x,
                                                      float* __restrict__ s) {
    const int gwave = (blockIdx.x * blockDim.x + threadIdx.x) >> 6;  // pair id
    const int lane  = threadIdx.x & 63;
    if (gwave >= BATCH * C_IN) return;

    const float4* p = reinterpret_cast<const float4*>(x + (size_t)gwave * SPATIAL);
    float acc = 0.0f;
#pragma unroll
    for (int j = 0; j < 3; ++j) {                 // 192 float4
        float4 v = p[lane + 64 * j];
        acc += fabsf(v.x) + fabsf(v.y) + fabsf(v.z) + fabsf(v.w);
    }
    if (lane < 4) {                               // tail 4 float4
        float4 v = p[192 + lane];
        acc += fabsf(v.x) + fabsf(v.y) + fabsf(v.z) + fabsf(v.w);
    }
#pragma unroll
    for (int off = 32; off; off >>= 1) acc += __shfl_xor(acc, off);
    if (lane == 0) s[gwave] = acc * (1.0f / (float)SPATIAL);
}

// ---------------------------------------------------------------------------
// Kernel 2: per batch row -- gate GEMV + relu, stable-rank top-K-smallest
// zeroing, renormalize.  One block (512 threads, 8 waves) per batch element.
// Stable rank (#{g_j < g_t} + #{j<t : g_j == g_t}) reproduces
// jax.lax.top_k(-g, K) lower-index-first tie-break exactly (ReLU mass-ties
// at 0 make this matter).
// ---------------------------------------------------------------------------
__global__ __launch_bounds__(512) void gate_kernel(const float* __restrict__ s,
                                                   const float* __restrict__ W,
                                                   const float* __restrict__ bias,
                                                   float* __restrict__ out) {
    const int b    = blockIdx.x;
    const int t    = threadIdx.x;        // 0..511
    const int lane = t & 63;
    const int wid  = t >> 6;             // 0..7

    __shared__ float sh_s[C_IN];
    __shared__ float sh_g[C_OUT];
    __shared__ float sh_red[8];

    sh_s[t] = s[b * C_IN + t];
    __syncthreads();

    // hoist this wave's s fragment into registers (same for all 64 outputs)
    float s_reg[8];
#pragma unroll
    for (int j = 0; j < 8; ++j) s_reg[j] = sh_s[lane + 64 * j];

    // each wave computes 64 gate outputs; W row reads are coalesced (256B/load)
    for (int i = 0; i < 64; ++i) {
        const int c = wid * 64 + i;
        const float* wr = W + (size_t)c * (C_IN + 1);
        float acc = 0.0f;
#pragma unroll
        for (int j = 0; j < 8; ++j) acc += wr[lane + 64 * j] * s_reg[j];
        if (lane == 0) acc += RATE * wr[C_IN];       // rate column
#pragma unroll
        for (int off = 32; off; off >>= 1) acc += __shfl_xor(acc, off);
        if (lane == 0) {
            float g = acc + bias[c];
            sh_g[c] = g > 0.0f ? g : 0.0f;           // relu
        }
    }
    __syncthreads();

    // stable rank of this thread's element among the row
    const float g = sh_g[t];
    int rank = 0;
    for (int j = 0; j < C_OUT; ++j) {                // LDS broadcast reads
        const float gj = sh_g[j];
        rank += (gj < g) | ((gj == g) & (j < t));
    }
    const float kept = (rank >= KSMALL) ? g : 0.0f;

    // block-reduce sum of kept values
    float sum = kept;
#pragma unroll
    for (int off = 32; off; off >>= 1) sum += __shfl_xor(sum, off);
    if (lane == 0) sh_red[wid] = sum;
    __syncthreads();
    if (t == 0) {
        float tot = 0.0f;
#pragma unroll
        for (int w = 0; w < 8; ++w) tot += sh_red[w];
        sh_red[0] = tot;
    }
    __syncthreads();

    out[b * C_OUT + t] = kept * ((float)C_OUT / sh_red[0]);
}

// ---------------------------------------------------------------------------
extern "C" void kernel_launch(void* const* d_in, const int* in_sizes, int n_in,
                              void* d_out, int out_size, void* d_ws, size_t ws_size,
                              hipStream_t stream) {
    const float* x    = (const float*)d_in[0];   // [64,512,28,28]
    const float* W    = (const float*)d_in[1];   // [512,513]
    const float* bias = (const float*)d_in[2];   // [512]
    float* out        = (float*)d_out;           // [64,512] (x1x1)
    float* s          = (float*)d_ws;            // [64,512] scratch

    // Phase 1: abs-mean reduction. 32768 waves, 4 waves/block.
    const int pairs  = BATCH * C_IN;
    const int blocks = pairs / 4;                // 8192 blocks x 256 threads
    absmean_kernel<<<blocks, 256, 0, stream>>>(x, s);

    // Phase 2: gate + topk-zero + renormalize. One block per batch row.
    gate_kernel<<<BATCH, 512, 0, stream>>>(s, W, bias, out);
}

// Round 3
// 174.497 us; speedup vs baseline: 1.2523x; 1.2523x over previous
//
#include <hip/hip_runtime.h>
#include <hip/hip_bf16.h>

#define BATCH   64
#define C_IN    512
#define C_OUT   512
#define SPATIAL 784          // 28*28
#define KSMALL  256          // K = C_OUT * 0.5
#define RATE    0.5f

// ---------------------------------------------------------------------------
// Kernel 1: s[b][c] = mean(|x[b,c,:,:]|).  One wave per (b,c) pair.
// 784 floats = 196 float4 per pair, contiguous. Reads 102.8 MB total.
// ---------------------------------------------------------------------------
__global__ __launch_bounds__(256) void absmean_kernel(const float* __restrict__ x,
                                                      float* __restrict__ s) {
    const int gwave = (blockIdx.x * blockDim.x + threadIdx.x) >> 6;  // pair id
    const int lane  = threadIdx.x & 63;
    if (gwave >= BATCH * C_IN) return;

    const float4* p = reinterpret_cast<const float4*>(x + (size_t)gwave * SPATIAL);
    float acc = 0.0f;
#pragma unroll
    for (int j = 0; j < 3; ++j) {                 // 192 float4
        float4 v = p[lane + 64 * j];
        acc += fabsf(v.x) + fabsf(v.y) + fabsf(v.z) + fabsf(v.w);
    }
    if (lane < 4) {                               // tail 4 float4
        float4 v = p[192 + lane];
        acc += fabsf(v.x) + fabsf(v.y) + fabsf(v.z) + fabsf(v.w);
    }
#pragma unroll
    for (int off = 32; off; off >>= 1) acc += __shfl_xor(acc, off);
    if (lane == 0) s[gwave] = acc * (1.0f / (float)SPATIAL);
}

// ---------------------------------------------------------------------------
// Kernel 2: gate GEMV, one WAVE per output (b,c).  32768 waves -> 8192
// blocks: full-chip occupancy, no serial per-output loop (R2's 72us bug:
// 64 blocks x serial 64-iter reduce chain).  W row reads are 256B/instr
// coalesced; W (1.05 MB) is L2/L3-resident after first touch.
// ---------------------------------------------------------------------------
__global__ __launch_bounds__(256) void gemv_kernel(const float* __restrict__ s,
                                                   const float* __restrict__ W,
                                                   const float* __restrict__ bias,
                                                   float* __restrict__ g) {
    const int gwave = (blockIdx.x * blockDim.x + threadIdx.x) >> 6;  // 0..32767
    const int lane  = threadIdx.x & 63;
    const int b = gwave >> 9;        // / C_OUT
    const int c = gwave & (C_OUT - 1);

    const float* wr = W + (size_t)c * (C_IN + 1);
    const float* sr = s + b * C_IN;
    float acc = 0.0f;
#pragma unroll
    for (int j = 0; j < 8; ++j)
        acc += wr[lane + 64 * j] * sr[lane + 64 * j];
    if (lane == 0) acc += RATE * wr[C_IN];        // rate column
#pragma unroll
    for (int off = 32; off; off >>= 1) acc += __shfl_xor(acc, off);
    if (lane == 0) {
        float v = acc + bias[c];
        g[gwave] = v > 0.0f ? v : 0.0f;           // relu
    }
}

// ---------------------------------------------------------------------------
// Kernel 3: per batch row -- stable-rank top-K-smallest zeroing + renorm.
// rank = #{g_j < g_t} + #{j<t : g_j == g_t} reproduces lax.top_k(-g,K)
// lower-index-first tie-break exactly.  float4 LDS reads (broadcast,
// conflict-free) cut LDS issue count 4x vs scalar.
// ---------------------------------------------------------------------------
__global__ __launch_bounds__(512) void topk_kernel(const float* __restrict__ g,
                                                   float* __restrict__ out) {
    const int b    = blockIdx.x;
    const int t    = threadIdx.x;        // 0..511
    const int lane = t & 63;
    const int wid  = t >> 6;

    __shared__ float sh_g[C_OUT];
    __shared__ float sh_red[8];

    const float gv = g[b * C_OUT + t];
    sh_g[t] = gv;
    __syncthreads();

    const float4* shv = reinterpret_cast<const float4*>(sh_g);
    int rank = 0;
#pragma unroll 8
    for (int j4 = 0; j4 < C_OUT / 4; ++j4) {
        const float4 v = shv[j4];
        const int j = j4 * 4;
        rank += (v.x < gv) | ((v.x == gv) & (j + 0 < t));
        rank += (v.y < gv) | ((v.y == gv) & (j + 1 < t));
        rank += (v.z < gv) | ((v.z == gv) & (j + 2 < t));
        rank += (v.w < gv) | ((v.w == gv) & (j + 3 < t));
    }
    const float kept = (rank >= KSMALL) ? gv : 0.0f;

    float sum = kept;
#pragma unroll
    for (int off = 32; off; off >>= 1) sum += __shfl_xor(sum, off);
    if (lane == 0) sh_red[wid] = sum;
    __syncthreads();
    if (t == 0) {
        float tot = 0.0f;
#pragma unroll
        for (int w = 0; w < 8; ++w) tot += sh_red[w];
        sh_red[0] = tot;
    }
    __syncthreads();

    out[b * C_OUT + t] = kept * ((float)C_OUT / sh_red[0]);
}

// ---------------------------------------------------------------------------
extern "C" void kernel_launch(void* const* d_in, const int* in_sizes, int n_in,
                              void* d_out, int out_size, void* d_ws, size_t ws_size,
                              hipStream_t stream) {
    const float* x    = (const float*)d_in[0];   // [64,512,28,28]
    const float* W    = (const float*)d_in[1];   // [512,513]
    const float* bias = (const float*)d_in[2];   // [512]
    float* out        = (float*)d_out;           // [64,512] (x1x1)
    float* s          = (float*)d_ws;                        // [64,512]
    float* g          = (float*)d_ws + BATCH * C_IN;         // [64,512]

    // Phase 1: abs-mean reduction. 32768 waves, 4 waves/block.
    absmean_kernel<<<BATCH * C_IN / 4, 256, 0, stream>>>(x, s);

    // Phase 2: GEMV, one wave per (b,c) output. 8192 blocks.
    gemv_kernel<<<BATCH * C_OUT / 4, 256, 0, stream>>>(s, W, bias, g);

    // Phase 3: top-K zero + renormalize. One block per batch row.
    topk_kernel<<<BATCH, 512, 0, stream>>>(g, out);
}

// Round 4
// 172.911 us; speedup vs baseline: 1.2638x; 1.0092x over previous
//
#include <hip/hip_runtime.h>
#include <hip/hip_bf16.h>

#define BATCH   64
#define C_IN    512
#define C_OUT   512
#define SPATIAL 784          // 28*28
#define KSMALL  256          // K = C_OUT * 0.5
#define RATE    0.5f

// ---------------------------------------------------------------------------
// Kernel 1: s[b][c] = mean(|x[b,c,:,:]|).  One wave per (b,c) pair.
// Reads 102.8 MB total, fully coalesced float4 -> BW-bound, ~17-20 us.
// ---------------------------------------------------------------------------
__global__ __launch_bounds__(256) void absmean_kernel(const float* __restrict__ x,
                                                      float* __restrict__ s) {
    const int gwave = (blockIdx.x * blockDim.x + threadIdx.x) >> 6;  // pair id
    const int lane  = threadIdx.x & 63;
    if (gwave >= BATCH * C_IN) return;

    const float4* p = reinterpret_cast<const float4*>(x + (size_t)gwave * SPATIAL);
    float acc = 0.0f;
#pragma unroll
    for (int j = 0; j < 3; ++j) {                 // 192 float4
        float4 v = p[lane + 64 * j];
        acc += fabsf(v.x) + fabsf(v.y) + fabsf(v.z) + fabsf(v.w);
    }
    if (lane < 4) {                               // tail 4 float4
        float4 v = p[192 + lane];
        acc += fabsf(v.x) + fabsf(v.y) + fabsf(v.z) + fabsf(v.w);
    }
#pragma unroll
    for (int off = 32; off; off >>= 1) acc += __shfl_xor(acc, off);
    if (lane == 0) s[gwave] = acc * (1.0f / (float)SPATIAL);
}

// ---------------------------------------------------------------------------
// Kernel 2: gate GEMV, 4 outputs per wave (R3 was 1/wave -> latency-chain
// bound at 28us combined with topk).  s loads amortized 4x into registers;
// 4 independent shfl butterflies interleave (ILP); lane0 stores a float4.
// W row reads stay coalesced (256B/instr).  2048 blocks.
// ---------------------------------------------------------------------------
__global__ __launch_bounds__(256) void gemv_kernel(const float* __restrict__ s,
                                                   const float* __restrict__ W,
                                                   const float* __restrict__ bias,
                                                   float* __restrict__ g) {
    const int gwave = (blockIdx.x * blockDim.x + threadIdx.x) >> 6;  // 0..8191
    const int lane  = threadIdx.x & 63;
    const int b  = gwave >> 7;               // / 128 waves per batch row
    const int c0 = (gwave & 127) * 4;        // 4 consecutive outputs

    const float* sr = s + b * C_IN;
    float s_reg[8];
#pragma unroll
    for (int j = 0; j < 8; ++j) s_reg[j] = sr[lane + 64 * j];

    float acc[4];
#pragma unroll
    for (int o = 0; o < 4; ++o) {
        const float* wr = W + (size_t)(c0 + o) * (C_IN + 1);
        float a = 0.0f;
#pragma unroll
        for (int j = 0; j < 8; ++j) a += wr[lane + 64 * j] * s_reg[j];
        if (lane == 0) a += RATE * wr[C_IN];         // rate column
        acc[o] = a;
    }
    // 4 independent butterflies, interleaved by the scheduler
#pragma unroll
    for (int off = 32; off; off >>= 1) {
#pragma unroll
        for (int o = 0; o < 4; ++o) acc[o] += __shfl_xor(acc[o], off);
    }
    if (lane == 0) {
        float4 r;
        r.x = fmaxf(acc[0] + bias[c0 + 0], 0.0f);
        r.y = fmaxf(acc[1] + bias[c0 + 1], 0.0f);
        r.z = fmaxf(acc[2] + bias[c0 + 2], 0.0f);
        r.w = fmaxf(acc[3] + bias[c0 + 3], 0.0f);
        *reinterpret_cast<float4*>(g + b * C_OUT + c0) = r;
    }
}

// ---------------------------------------------------------------------------
// Kernel 3: per batch row -- stable-rank top-K-smallest zeroing + renorm.
// rank = #{g_j < g_t} + #{j<t : g_j == g_t} reproduces lax.top_k(-g,K)
// lower-index-first tie-break exactly (verified absmax 0.0 in R2/R3).
// ---------------------------------------------------------------------------
__global__ __launch_bounds__(512) void topk_kernel(const float* __restrict__ g,
                                                   float* __restrict__ out) {
    const int b    = blockIdx.x;
    const int t    = threadIdx.x;        // 0..511
    const int lane = t & 63;
    const int wid  = t >> 6;

    __shared__ float sh_g[C_OUT];
    __shared__ float sh_red[8];

    const float gv = g[b * C_OUT + t];
    sh_g[t] = gv;
    __syncthreads();

    const float4* shv = reinterpret_cast<const float4*>(sh_g);
    int rank = 0;
#pragma unroll 8
    for (int j4 = 0; j4 < C_OUT / 4; ++j4) {
        const float4 v = shv[j4];
        const int j = j4 * 4;
        rank += (v.x < gv) | ((v.x == gv) & (j + 0 < t));
        rank += (v.y < gv) | ((v.y == gv) & (j + 1 < t));
        rank += (v.z < gv) | ((v.z == gv) & (j + 2 < t));
        rank += (v.w < gv) | ((v.w == gv) & (j + 3 < t));
    }
    const float kept = (rank >= KSMALL) ? gv : 0.0f;

    float sum = kept;
#pragma unroll
    for (int off = 32; off; off >>= 1) sum += __shfl_xor(sum, off);
    if (lane == 0) sh_red[wid] = sum;
    __syncthreads();
    if (t == 0) {
        float tot = 0.0f;
#pragma unroll
        for (int w = 0; w < 8; ++w) tot += sh_red[w];
        sh_red[0] = tot;
    }
    __syncthreads();

    out[b * C_OUT + t] = kept * ((float)C_OUT / sh_red[0]);
}

// ---------------------------------------------------------------------------
extern "C" void kernel_launch(void* const* d_in, const int* in_sizes, int n_in,
                              void* d_out, int out_size, void* d_ws, size_t ws_size,
                              hipStream_t stream) {
    const float* x    = (const float*)d_in[0];   // [64,512,28,28]
    const float* W    = (const float*)d_in[1];   // [512,513]
    const float* bias = (const float*)d_in[2];   // [512]
    float* out        = (float*)d_out;           // [64,512] (x1x1)
    float* s          = (float*)d_ws;                        // [64,512]
    float* g          = (float*)d_ws + BATCH * C_IN;         // [64,512]

    // Phase 1: abs-mean reduction. 32768 waves, 4 waves/block.
    absmean_kernel<<<BATCH * C_IN / 4, 256, 0, stream>>>(x, s);

    // Phase 2: GEMV, 4 outputs per wave. 2048 blocks.
    gemv_kernel<<<BATCH * C_OUT / 16, 256, 0, stream>>>(s, W, bias, g);

    // Phase 3: top-K zero + renormalize. One block per batch row.
    topk_kernel<<<BATCH, 512, 0, stream>>>(g, out);
}